// Round 10
// baseline (17305.736 us; speedup 1.0000x reference)
//
#include <hip/hip_runtime.h>
#include <hip/hip_bf16.h>

// ---------------------------------------------------------------------------
// Lattice LSTM (bidirectional) — round 9: round-7 residency design with a
// tag-fused exchange (one L3 latency, no flags, no drain barrier).
//
//   2 CUs per direction (same-XCD pairs {0,8},{1,9}); side0 owns v = h@W_hh,
//   side1 owns u = h@wW_hh; 12 tiles/wave resident (VGPR+AGPR, builtin MFMA,
//   __launch_bounds__(256,1) = 512 unified regs/wave). aW_hh in LDS on both.
//
//   Exchange: 384 x 8B words per side/step, each = (tag:t+1 | 2 bf16), fired
//   directly from S1 accumulator registers. Receiver polls its own words at
//   the point the data is needed (side0: u before len-2 word cells; side1: v
//   before merge). 2-slot parity ping-pong; xb memset per launch kills
//   cross-replay stale-tag matches.
// ---------------------------------------------------------------------------

#define TSEQ 2048
#define KEND 8
#define DEMB 100
#define H    256
#define H3   768
#define WD   300
#define CCLS 18
#define NTH  256

typedef __attribute__((ext_vector_type(8))) short bf16x8;
typedef __attribute__((ext_vector_type(4))) float f32x4;

// LDS offsets (bytes)
#define LO_AT  0        // alpha weight tiles [16][8 ks][64 lanes][16B] 131072
#define LO_A1  131072   // h(t-1) row bf16[256]                            512
#define LO_VS  131584   // v stage bf16[768]                              1536
#define LO_UR  133120   // u-ring bf16 [7][768]                          10752
#define LO_RC  143872   // ringC f32 [8][256]                             8192
#define LO_A2  152064   // cw rows bf16 [8][264] (528B stride)            4224
#define LO_AWS 156288   // awS bf16 [8][256]                              4096
#define LO_MT  160384   // meta int [2][32]: {nw, slot[8], start[8]}       256
#define SMEM_SCAN 160640

__device__ __forceinline__ float sigf(float x) { return 1.0f / (1.0f + expf(-x)); }
__device__ __forceinline__ float bf2f(unsigned u) { return __uint_as_float(u << 16); }
__device__ __forceinline__ unsigned f2bf(float f) {
  union { float f; unsigned u; } x; x.f = f;
  unsigned r = x.u + 0x7fffu + ((x.u >> 16) & 1u);   // RNE
  return r >> 16;
}

// ---------------- K0: pack weights into MFMA-fragment layout (bf16) ---------
__global__ __launch_bounds__(64) void k_pack(
    const float* __restrict__ W_hh_f, const float* __restrict__ wW_hh_f, const float* __restrict__ aW_hh_f,
    const float* __restrict__ W_hh_b, const float* __restrict__ wW_hh_b, const float* __restrict__ aW_hh_b,
    unsigned short* __restrict__ Wpk)
{
  const int T = blockIdx.x, dir = blockIdx.y;
  const int lane = threadIdx.x;
  const float* Wg = dir ? W_hh_b  : W_hh_f;
  const float* Ww = dir ? wW_hh_b : wW_hh_f;
  const float* Wa = dir ? aW_hh_b : aW_hh_f;
  for (int ks = 0; ks < 8; ++ks) {
    bf16x8 sv;
#pragma unroll
    for (int e = 0; e < 8; ++e) {
      const int k = ks * 32 + (lane >> 4) * 8 + e;
      float f;
      if (T < 96) {
        const int c = T * 16 + (lane & 15);
        f = (c < H3) ? Wg[(size_t)k * H3 + c] : Ww[(size_t)k * H3 + (c - H3)];
      } else {
        const int c = (T - 96) * 16 + (lane & 15);
        f = Wa[(size_t)k * H + c];
      }
      sv[e] = (short)f2bf(f);
    }
    *(bf16x8*)(Wpk + (((size_t)dir * 112 + T) * 8 + ks) * 512 + lane * 8) = sv;
  }
}

// ---------------- K1: char embedding -> gate / alpha input preacts ----------
__global__ __launch_bounds__(256) void k_embed(
    const int* __restrict__ inputs, const float* __restrict__ E,
    const float* __restrict__ W_ih_f, const float* __restrict__ b_f,
    const float* __restrict__ aW_ih_f, const float* __restrict__ ab_f,
    const float* __restrict__ W_ih_b, const float* __restrict__ b_b,
    const float* __restrict__ aW_ih_b, const float* __restrict__ ab_b,
    __hip_bfloat16* __restrict__ xg, float* __restrict__ xa)
{
  const int t = blockIdx.x, dir = blockIdx.y;
  const int tid = threadIdx.x;
  const float* W_ih = dir ? W_ih_b : W_ih_f;
  const float* bb   = dir ? b_b    : b_f;
  const float* aW   = dir ? aW_ih_b : aW_ih_f;
  const float* ab   = dir ? ab_b   : ab_f;
  const int src = dir ? (TSEQ - 1 - t) : t;

  __shared__ float xr[DEMB];
  if (tid < DEMB) xr[tid] = E[(size_t)inputs[src] * DEMB + tid];
  __syncthreads();

  float a0 = bb[tid], a1 = bb[H + tid], a2 = bb[2 * H + tid], a3 = ab[tid];
  for (int r = 0; r < DEMB; r += 4) {
    const float4 e4 = *reinterpret_cast<const float4*>(&xr[r]);
    const float ev[4] = {e4.x, e4.y, e4.z, e4.w};
#pragma unroll
    for (int kk = 0; kk < 4; ++kk) {
      const float* wp = W_ih + (size_t)(r + kk) * H3 + tid;
      a0 += ev[kk] * wp[0];
      a1 += ev[kk] * wp[H];
      a2 += ev[kk] * wp[2 * H];
      a3 += ev[kk] * aW[(size_t)(r + kk) * H + tid];
    }
  }
  __hip_bfloat16* xgrow = xg + ((size_t)dir * TSEQ + t) * H3;
  xgrow[tid]         = __float2bfloat16(a0);
  xgrow[H + tid]     = __float2bfloat16(a1);
  xgrow[2 * H + tid] = __float2bfloat16(a2);
  xa[((size_t)dir * TSEQ + t) * H + tid] = a3;
}

// ---------------- K2: word-gate preacts (valid slots only), bf16 out --------
__global__ __launch_bounds__(256) void k_wordgates(
    const int* __restrict__ fw_ids, const int* __restrict__ fw_mask,
    const int* __restrict__ bw_ids, const int* __restrict__ bw_mask,
    const float* __restrict__ word_table,
    const float* __restrict__ wW_ih_f, const float* __restrict__ wb_f,
    const float* __restrict__ wW_ih_b, const float* __restrict__ wb_b,
    __hip_bfloat16* __restrict__ wg)
{
  const int t = blockIdx.x, dir = blockIdx.y;
  const int tid = threadIdx.x;
  const int* ids = (dir ? bw_ids : fw_ids) + t * KEND;
  const int* msk = (dir ? bw_mask : fw_mask) + t * KEND;
  const float* wW = dir ? wW_ih_b : wW_ih_f;
  const float* wb = dir ? wb_b    : wb_f;

  __shared__ float we[KEND][WD];
  for (int w = 0; w < KEND; ++w) {
    if (msk[w]) {
      const float* src = word_table + (size_t)ids[w] * WD;
      for (int i = tid; i < WD; i += 256) we[w][i] = src[i];
    }
  }
  __syncthreads();

  __hip_bfloat16* out = wg + ((size_t)dir * TSEQ + t) * KEND * H3;
  for (int w = 0; w < KEND; ++w) {
    if (!msk[w]) continue;
    float a0 = wb[tid], a1 = wb[H + tid], a2 = wb[2 * H + tid];
    for (int r = 0; r < WD; r += 4) {
      const float4 e4 = *reinterpret_cast<const float4*>(&we[w][r]);
      const float ev[4] = {e4.x, e4.y, e4.z, e4.w};
#pragma unroll
      for (int kk = 0; kk < 4; ++kk) {
        const float* wp = wW + (size_t)(r + kk) * H3 + tid;
        a0 += ev[kk] * wp[0];
        a1 += ev[kk] * wp[H];
        a2 += ev[kk] * wp[2 * H];
      }
    }
    out[w * H3 + tid]         = __float2bfloat16(a0);
    out[w * H3 + H + tid]     = __float2bfloat16(a1);
    out[w * H3 + 2 * H + tid] = __float2bfloat16(a2);
  }
}

// ---------------- K3: scan; active blocks {0,8}=dir0, {1,9}=dir1 ------------
__global__ __launch_bounds__(NTH, 1) void k_scan(
    const __hip_bfloat16* __restrict__ xg, const float* __restrict__ xa,
    const __hip_bfloat16* __restrict__ wgG, float* __restrict__ hseq,
    const int* __restrict__ fw_start, const int* __restrict__ fw_mask,
    const int* __restrict__ bw_start, const int* __restrict__ bw_mask,
    const unsigned short* __restrict__ Wpk,
    unsigned long long* __restrict__ xb)
{
  const int gid = blockIdx.x;
  if (gid != 0 && gid != 1 && gid != 8 && gid != 9) return;  // same-XCD pairs
  const int dir  = gid & 1;
  const int side = gid >> 3;

  extern __shared__ char smem[];
  unsigned short* A1_16 = (unsigned short*)(smem + LO_A1);
  unsigned short* vS16  = (unsigned short*)(smem + LO_VS);
  unsigned short* ur16  = (unsigned short*)(smem + LO_UR);
  float* ringC = (float*)(smem + LO_RC);
  unsigned short* awS16 = (unsigned short*)(smem + LO_AWS);
  int* metaI = (int*)(smem + LO_MT);

  const int tid  = threadIdx.x;
  const int lane = tid & 63;
  const int wv   = tid >> 6;          // wave 0..3
  const int lmod = lane & 15;
  const int lgrp = lane >> 4;

  const int* startA = dir ? bw_start : fw_start;
  const int* maskA  = dir ? bw_mask  : fw_mask;
  const char* WpkD = (const char*)(Wpk + (size_t)dir * 112 * 8 * 512);

  unsigned long long* myPay = xb + (size_t)((dir * 2 + side) * 2) * 384;
  const unsigned long long* peerPay = xb + (size_t)((dir * 2 + (side ^ 1)) * 2) * 384;

  // ---- one-time: 12 gate tiles/wave -> registers (builtin MFMA path) -------
  bf16x8 rW[12][8];
  {
    const char* rp = WpkD + (size_t)(side * 48 + wv * 12) * 8192 + lane * 16;
#pragma unroll
    for (int n = 0; n < 12; ++n)
#pragma unroll
      for (int ks = 0; ks < 8; ++ks)
        rW[n][ks] = *(const bf16x8*)(rp + (n * 8 + ks) * 1024);
  }
  // ---- one-time: 16 alpha tiles -> LDS -------------------------------------
  for (int o = tid * 16; o < 131072; o += NTH * 16)
    *(uint4*)(smem + LO_AT + o) = *(const uint4*)(WpkD + (size_t)96 * 8192 + o);
  // zero A1 / A2 / ringC
  if (tid < 32) *(uint4*)(smem + LO_A1 + tid * 16) = uint4{0, 0, 0, 0};
  for (int o = tid * 16; o < 4224; o += NTH * 16)
    *(uint4*)(smem + LO_A2 + o) = uint4{0, 0, 0, 0};
  for (int o = tid * 16; o < 8192; o += NTH * 16)
    *(uint4*)(smem + LO_RC + o) = uint4{0, 0, 0, 0};

  // ---- prologue: prefetch t=0, compact meta[0] -----------------------------
  unsigned nxI = 0, nxO = 0, nxG = 0; float nxA = 0.f;
  unsigned cxI = 0, cxO = 0, cxG = 0; float cxA = 0.f;
  int nmt = 0;
  {
    const unsigned short* xr = (const unsigned short*)(xg + (size_t)dir * TSEQ * H3);
    nxI = xr[tid]; nxO = xr[H + tid]; nxG = xr[2 * H + tid];
    nxA = xa[(size_t)dir * TSEQ * H + tid];
    if (wv == 3) {
      if (lane < 8) nmt = maskA[lane];
      else if (lane < 16) nmt = startA[lane - 8];
    }
  }
  __syncthreads();
  if (wv == 3) {
    int mAll[8], sAll[8];
#pragma unroll
    for (int s = 0; s < 8; ++s) { mAll[s] = __shfl(nmt, s); sAll[s] = __shfl(nmt, 8 + s); }
    if (lane == 0) {
      int n = 0;
      for (int s = 0; s < 8; ++s)
        if (mAll[s]) { metaI[1 + n] = s; metaI[9 + n] = sAll[s]; ++n; }
      metaI[0] = n;
    }
  }
  cxI = nxI; cxO = nxO; cxG = nxG; cxA = nxA;
  __syncthreads();

  // ---- main loop -----------------------------------------------------------
  for (int t = 0; t < TSEQ; ++t) {
    const int par = t & 1;
    const int* mp = metaI + par * 32;
    const int nw = mp[0];
    const int us7 = (t + 6) % 7;                    // u-ring slot for s = t-1
    unsigned short* stage16 = side ? (ur16 + us7 * 768) : vS16;
    unsigned short* rcv16   = side ? vS16 : (ur16 + us7 * 768);

    // -- issue wg(t) loads for this step's word cells (registers) ------------
    unsigned short wgv[24];
#pragma unroll
    for (int it = 0; it < 8; ++it) {
      const int u0 = tid + it * NTH;
      if (u0 < nw * 256) {
        const int w = u0 >> 8, j = u0 & 255;
        const int slot = mp[1 + w];
        const unsigned short* wgp =
            (const unsigned short*)wgG + ((size_t)(dir * TSEQ + t) * KEND + slot) * H3 + j;
        wgv[it * 3 + 0] = wgp[0];
        wgv[it * 3 + 1] = wgp[256];
        wgv[it * 3 + 2] = wgp[512];
      }
    }

    // ======== S1: own half of [v|u] = h(t-1) @ W; publish from registers ====
#pragma unroll
    for (int g = 0; g < 2; ++g) {
      f32x4 acc[6];
#pragma unroll
      for (int n = 0; n < 6; ++n) acc[n] = f32x4{0.f, 0.f, 0.f, 0.f};
#pragma unroll
      for (int ks = 0; ks < 8; ++ks) {
        const bf16x8 av = *(const bf16x8*)(smem + LO_A1 + ks * 64 + lgrp * 16);
#pragma unroll
        for (int n = 0; n < 6; ++n)
          acc[n] = __builtin_amdgcn_mfma_f32_16x16x32_bf16(av, rW[g * 6 + n][ks], acc[n], 0, 0, 0);
      }
#pragma unroll
      for (int n = 0; n < 6; ++n) {
        const unsigned hb = f2bf(acc[n][0]) & 0xffffu;
        const unsigned ob = (unsigned)__shfl_down((int)hb, 1) & 0xffffu;
        if (lane < 16) {
          const int tix = wv * 12 + g * 6 + n;
          stage16[tix * 16 + lane] = (unsigned short)hb;   // own LDS copy
          if (!(lane & 1)) {                               // tag-fused publish
            const unsigned long long q =
                ((unsigned long long)(unsigned)(t + 1) << 32) |
                (unsigned long long)(hb | (ob << 16));
            __hip_atomic_store(myPay + par * 384 + tix * 8 + (lane >> 1), q,
                               __ATOMIC_RELAXED, __HIP_MEMORY_SCOPE_AGENT);
          }
        }
      }
    }

    // -- prefetch t+1 inputs (consumed next step) ----------------------------
    {
      const int tn = (t + 1 < TSEQ) ? t + 1 : TSEQ - 1;
      const unsigned short* xr = (const unsigned short*)(xg + ((size_t)dir * TSEQ + tn) * H3);
      nxI = xr[tid]; nxO = xr[H + tid]; nxG = xr[2 * H + tid];
      nxA = xa[((size_t)dir * TSEQ + tn) * H + tid];
      if (wv == 3) {
        if (lane < 8) nmt = maskA[tn * KEND + lane];
        else if (lane < 16) nmt = startA[tn * KEND + (lane - 8)];
      }
    }
    __syncthreads();   // barA: stage16 (own half) visible

    if (side == 0) {
      // ---- S2a: word cells for starts <= t-2 (local u available) ----------
      if (nw > 0) {
#pragma unroll
        for (int it = 0; it < 8; ++it) {
          const int u0 = tid + it * NTH;
          if (u0 < nw * 256) {
            const int w = u0 >> 8, j = u0 & 255;
            const int s = mp[9 + w];
            if (s != t - 1) {
              const unsigned short* ur = ur16 + (s % 7) * 768;
              const float wi  = bf2f(wgv[it * 3 + 0]) + bf2f(ur[j]);
              const float wf  = bf2f(wgv[it * 3 + 1]) + bf2f(ur[256 + j]);
              const float wgg = bf2f(wgv[it * 3 + 2]) + bf2f(ur[512 + j]);
              const float cs  = ringC[(s & 7) * 256 + j];
              const float cv  = sigf(wf) * cs + sigf(wi) * tanhf(wgg);
              *(unsigned short*)(smem + LO_A2 + w * 528 + j * 2) = (unsigned short)f2bf(cv);
            }
          }
        }
      }
      // ---- receive u(t-1) (tag-poll, at point of need) ---------------------
      if (tid < 192) {
        unsigned long long q;
        do { q = __hip_atomic_load(peerPay + par * 384 + tid, __ATOMIC_RELAXED, __HIP_MEMORY_SCOPE_AGENT); }
        while ((unsigned)(q >> 32) != (unsigned)(t + 1));
        *(unsigned*)((char*)rcv16 + tid * 4) = (unsigned)q;
        do { q = __hip_atomic_load(peerPay + par * 384 + 192 + tid, __ATOMIC_RELAXED, __HIP_MEMORY_SCOPE_AGENT); }
        while ((unsigned)(q >> 32) != (unsigned)(t + 1));
        *(unsigned*)((char*)rcv16 + (192 + tid) * 4) = (unsigned)q;
      }
      __syncthreads();   // barB: uring[us7] complete (recv)
      if (nw > 0) {
        // ---- S2b: len-2 word cells (need received u(t-1)) ------------------
#pragma unroll
        for (int it = 0; it < 8; ++it) {
          const int u0 = tid + it * NTH;
          if (u0 < nw * 256) {
            const int w = u0 >> 8, j = u0 & 255;
            const int s = mp[9 + w];
            if (s == t - 1) {
              const unsigned short* ur = ur16 + (s % 7) * 768;
              const float wi  = bf2f(wgv[it * 3 + 0]) + bf2f(ur[j]);
              const float wf  = bf2f(wgv[it * 3 + 1]) + bf2f(ur[256 + j]);
              const float wgg = bf2f(wgv[it * 3 + 2]) + bf2f(ur[512 + j]);
              const float cs  = ringC[(s & 7) * 256 + j];
              const float cv  = sigf(wf) * cs + sigf(wi) * tanhf(wgg);
              *(unsigned short*)(smem + LO_A2 + w * 528 + j * 2) = (unsigned short)f2bf(cv);
            }
          }
        }
        __syncthreads();   // barC: A2 complete
        // ---- S3: alpha matvec (4 LDS tiles/wave) ---------------------------
        {
          const int r2 = (lmod > 7) ? 7 : lmod;
          f32x4 ac[4];
#pragma unroll
          for (int m = 0; m < 4; ++m) ac[m] = f32x4{0.f, 0.f, 0.f, 0.f};
#pragma unroll
          for (int ks = 0; ks < 8; ++ks) {
            const bf16x8 a2v = *(const bf16x8*)(smem + LO_A2 + r2 * 528 + ks * 64 + lgrp * 16);
#pragma unroll
            for (int m = 0; m < 4; ++m) {
              const bf16x8 b = *(const bf16x8*)(smem + LO_AT + (size_t)(wv * 4 + m) * 8192 + ks * 1024 + lane * 16);
              ac[m] = __builtin_amdgcn_mfma_f32_16x16x32_bf16(a2v, b, ac[m], 0, 0, 0);
            }
          }
#pragma unroll
          for (int m = 0; m < 4; ++m)
#pragma unroll
            for (int r = 0; r < 4; ++r) {
              const int row = lgrp * 4 + r;
              if (row < nw) awS16[row * 256 + (wv * 4 + m) * 16 + lmod] = (unsigned short)f2bf(ac[m][r]);
            }
        }
        __syncthreads();   // barD: awS ready
      }
    } else {
      // ---- side1: all word cells (own u(t-1) is local) ---------------------
      if (nw > 0) {
#pragma unroll
        for (int it = 0; it < 8; ++it) {
          const int u0 = tid + it * NTH;
          if (u0 < nw * 256) {
            const int w = u0 >> 8, j = u0 & 255;
            const int s = mp[9 + w];
            const unsigned short* ur = ur16 + (s % 7) * 768;
            const float wi  = bf2f(wgv[it * 3 + 0]) + bf2f(ur[j]);
            const float wf  = bf2f(wgv[it * 3 + 1]) + bf2f(ur[256 + j]);
            const float wgg = bf2f(wgv[it * 3 + 2]) + bf2f(ur[512 + j]);
            const float cs  = ringC[(s & 7) * 256 + j];
            const float cv  = sigf(wf) * cs + sigf(wi) * tanhf(wgg);
            *(unsigned short*)(smem + LO_A2 + w * 528 + j * 2) = (unsigned short)f2bf(cv);
          }
        }
        __syncthreads();   // A2 ready
        {
          const int r2 = (lmod > 7) ? 7 : lmod;
          f32x4 ac[4];
#pragma unroll
          for (int m = 0; m < 4; ++m) ac[m] = f32x4{0.f, 0.f, 0.f, 0.f};
#pragma unroll
          for (int ks = 0; ks < 8; ++ks) {
            const bf16x8 a2v = *(const bf16x8*)(smem + LO_A2 + r2 * 528 + ks * 64 + lgrp * 16);
#pragma unroll
            for (int m = 0; m < 4; ++m) {
              const bf16x8 b = *(const bf16x8*)(smem + LO_AT + (size_t)(wv * 4 + m) * 8192 + ks * 1024 + lane * 16);
              ac[m] = __builtin_amdgcn_mfma_f32_16x16x32_bf16(a2v, b, ac[m], 0, 0, 0);
            }
          }
#pragma unroll
          for (int m = 0; m < 4; ++m)
#pragma unroll
            for (int r = 0; r < 4; ++r) {
              const int row = lgrp * 4 + r;
              if (row < nw) awS16[row * 256 + (wv * 4 + m) * 16 + lmod] = (unsigned short)f2bf(ac[m][r]);
            }
        }
      }
      // ---- receive v (needed only for merge; peer published long ago) ------
      if (tid < 192) {
        unsigned long long q;
        do { q = __hip_atomic_load(peerPay + par * 384 + tid, __ATOMIC_RELAXED, __HIP_MEMORY_SCOPE_AGENT); }
        while ((unsigned)(q >> 32) != (unsigned)(t + 1));
        *(unsigned*)((char*)rcv16 + tid * 4) = (unsigned)q;
        do { q = __hip_atomic_load(peerPay + par * 384 + 192 + tid, __ATOMIC_RELAXED, __HIP_MEMORY_SCOPE_AGENT); }
        while ((unsigned)(q >> 32) != (unsigned)(t + 1));
        *(unsigned*)((char*)rcv16 + (192 + tid) * 4) = (unsigned)q;
      }
      __syncthreads();   // vS16 (+awS) ready
    }

    // ======== S4: merge + state update (redundant, bit-identical) ===========
    {
      const int j = tid;
      const float i_s = sigf(bf2f(cxI) + bf2f(vS16[j]));
      const float o_s = sigf(bf2f(cxO) + bf2f(vS16[256 + j]));
      const float g_t = tanhf(bf2f(cxG) + bf2f(vS16[512 + j]));
      float cnew;
      if (nw > 0) {
        const float e_i = expf(i_s);
        float num = e_i * g_t, den = e_i;
        for (int w = 0; w < nw; ++w) {
          const float a  = sigf(cxA + bf2f(awS16[w * 256 + j]));
          const float ea = expf(a);
          num += ea * bf2f(*(const unsigned short*)(smem + LO_A2 + w * 528 + j * 2));
          den += ea;
        }
        cnew = num / den;
      } else {
        cnew = (1.f - i_s) * ringC[((t - 1) & 7) * 256 + j] + i_s * g_t;
      }
      const float hnew = o_s * tanhf(cnew);
      ringC[(t & 7) * 256 + j] = cnew;
      A1_16[j] = (unsigned short)f2bf(hnew);
      if ((side == 0) == (j < 128))                       // balanced skew
        hseq[((size_t)dir * TSEQ + t) * H + j] = hnew;
    }
    if (wv == 3) {
      int mAll[8], sAll[8];
#pragma unroll
      for (int s = 0; s < 8; ++s) { mAll[s] = __shfl(nmt, s); sAll[s] = __shfl(nmt, 8 + s); }
      if (lane == 0) {
        int* mq = metaI + ((t + 1) & 1) * 32;
        int n = 0;
        for (int s = 0; s < 8; ++s)
          if (mAll[s]) { mq[1 + n] = s; mq[9 + n] = sAll[s]; ++n; }
        mq[0] = n;
      }
    }
    cxI = nxI; cxO = nxO; cxG = nxG; cxA = nxA;
    __syncthreads();   // final bar: A1/ringC/meta ready for t+1
  }
}

// ---------------- K4: output projection -------------------------------------
__global__ __launch_bounds__(64) void k_proj(
    const float* __restrict__ hseq, const float* __restrict__ W_lin,
    const float* __restrict__ b_lin, float* __restrict__ out)
{
  const int t = blockIdx.x;
  const int tid = threadIdx.x;
  __shared__ float hrow[2 * H];
  for (int i = tid; i < H; i += 64) {
    hrow[i]     = hseq[(size_t)t * H + i];
    hrow[H + i] = hseq[((size_t)TSEQ + (TSEQ - 1 - t)) * H + i];
  }
  __syncthreads();
  if (tid < CCLS) {
    float acc = b_lin[tid];
    for (int j = 0; j < 2 * H; ++j) acc += hrow[j] * W_lin[(size_t)j * CCLS + tid];
    out[(size_t)t * CCLS + tid] = acc;
  }
}

// ---------------------------------------------------------------------------
extern "C" void kernel_launch(void* const* d_in, const int* in_sizes, int n_in,
                              void* d_out, int out_size, void* d_ws, size_t ws_size,
                              hipStream_t stream)
{
  const int* inputs   = (const int*)d_in[0];
  const int* fw_ids   = (const int*)d_in[1];
  const int* fw_start = (const int*)d_in[2];
  const int* fw_mask  = (const int*)d_in[3];
  const int* bw_ids   = (const int*)d_in[4];
  const int* bw_start = (const int*)d_in[5];
  const int* bw_mask  = (const int*)d_in[6];
  const float* E          = (const float*)d_in[8];
  const float* word_table = (const float*)d_in[9];
  const float* W_lin      = (const float*)d_in[10];
  const float* b_lin      = (const float*)d_in[11];
  const float* fw_W_ih  = (const float*)d_in[12];
  const float* fw_W_hh  = (const float*)d_in[13];
  const float* fw_b     = (const float*)d_in[14];
  const float* fw_aW_ih = (const float*)d_in[15];
  const float* fw_aW_hh = (const float*)d_in[16];
  const float* fw_ab    = (const float*)d_in[17];
  const float* fw_wW_ih = (const float*)d_in[18];
  const float* fw_wW_hh = (const float*)d_in[19];
  const float* fw_wb    = (const float*)d_in[20];
  const float* bw_W_ih  = (const float*)d_in[21];
  const float* bw_W_hh  = (const float*)d_in[22];
  const float* bw_b     = (const float*)d_in[23];
  const float* bw_aW_ih = (const float*)d_in[24];
  const float* bw_aW_hh = (const float*)d_in[25];
  const float* bw_ab    = (const float*)d_in[26];
  const float* bw_wW_ih = (const float*)d_in[27];
  const float* bw_wW_hh = (const float*)d_in[28];
  const float* bw_wb    = (const float*)d_in[29];

  char* p = (char*)d_ws;
  __hip_bfloat16* xg = (__hip_bfloat16*)p;  p += (size_t)2 * TSEQ * H3 * 2;        // 6.3 MB
  float* xa   = (float*)p;                  p += (size_t)2 * TSEQ * H * 4;         // 4.2 MB
  float* hseq = (float*)p;                  p += (size_t)2 * TSEQ * H * 4;         // 4.2 MB
  __hip_bfloat16* wg = (__hip_bfloat16*)p;  p += (size_t)2 * TSEQ * KEND * H3 * 2; // 50.3 MB
  unsigned short* Wpk = (unsigned short*)p; p += (size_t)2 * 112 * 8 * 512 * 2;    // 1.8 MB
  unsigned long long* xb = (unsigned long long*)p;                                  // 24.6 KB
  const size_t xb_bytes = (size_t)2 * 2 * 2 * 384 * 8;
  p += xb_bytes;

  hipFuncSetAttribute((const void*)k_scan,
                      hipFuncAttributeMaxDynamicSharedMemorySize, SMEM_SCAN);
  hipMemsetAsync(xb, 0, xb_bytes, stream);   // reset tags each launch (graph-safe)

  k_pack<<<dim3(112, 2), 64, 0, stream>>>(
      fw_W_hh, fw_wW_hh, fw_aW_hh, bw_W_hh, bw_wW_hh, bw_aW_hh, Wpk);
  k_embed<<<dim3(TSEQ, 2), 256, 0, stream>>>(
      inputs, E, fw_W_ih, fw_b, fw_aW_ih, fw_ab, bw_W_ih, bw_b, bw_aW_ih, bw_ab, xg, xa);
  k_wordgates<<<dim3(TSEQ, 2), 256, 0, stream>>>(
      fw_ids, fw_mask, bw_ids, bw_mask, word_table, fw_wW_ih, fw_wb, bw_wW_ih, bw_wb, wg);
  k_scan<<<16, NTH, SMEM_SCAN, stream>>>(
      xg, xa, wg, hseq, fw_start, fw_mask, bw_start, bw_mask, Wpk, xb);
  k_proj<<<TSEQ, 64, 0, stream>>>(hseq, W_lin, b_lin, (float*)d_out);
}

// Round 11
// 14214.749 us; speedup vs baseline: 1.2174x; 1.2174x over previous
//
#include <hip/hip_runtime.h>
#include <hip/hip_bf16.h>

// ---------------------------------------------------------------------------
// Lattice LSTM (bidirectional) — round 10: round-7 kernel (best measured,
// 14.4 ms) with exactly one schedule change: the exchange flag is published
// immediately after the payload-drain barrier, BEFORE the word-cell phase,
// so the peer's poll completes while we compute S2a (early-flag isolation).
// Plus: skip the S2b barrier on steps with no len-2 word (block-uniform).
//
//   2 CUs per direction (same-XCD pairs {0,8},{1,9}); side0 owns v = h@W_hh,
//   side1 owns u = h@wW_hh; 12 tiles/wave resident (VGPR+AGPR, builtin MFMA,
//   __launch_bounds__(256,1) = 512 unified regs/wave). aW_hh in LDS on both.
//   Word cells / alpha / merge run redundantly (bit-identical bf16 inputs).
// ---------------------------------------------------------------------------

#define TSEQ 2048
#define KEND 8
#define DEMB 100
#define H    256
#define H3   768
#define WD   300
#define CCLS 18
#define NTH  256

typedef __attribute__((ext_vector_type(8))) short bf16x8;
typedef __attribute__((ext_vector_type(4))) float f32x4;

// LDS offsets (bytes)
#define LO_AT  0        // alpha weight tiles [16][8 ks][64 lanes][16B] 131072
#define LO_A1  131072   // h(t-1) row bf16[256]                            512
#define LO_VS  131584   // v stage bf16[768]                              1536
#define LO_UR  133120   // u-ring bf16 [7][768]                          10752
#define LO_RC  143872   // ringC f32 [8][256]                             8192
#define LO_A2  152064   // cw rows bf16 [8][264] (528B stride)            4224
#define LO_AWS 156288   // awS bf16 [8][256]                              4096
#define LO_MT  160384   // meta int [2][32]: {nw, slot[8], start[8]}       256
#define SMEM_SCAN 160640

__device__ __forceinline__ float sigf(float x) { return 1.0f / (1.0f + expf(-x)); }
__device__ __forceinline__ float bf2f(unsigned u) { return __uint_as_float(u << 16); }
__device__ __forceinline__ unsigned f2bf(float f) {
  union { float f; unsigned u; } x; x.f = f;
  unsigned r = x.u + 0x7fffu + ((x.u >> 16) & 1u);   // RNE
  return r >> 16;
}

// ---------------- K0: pack weights into MFMA-fragment layout (bf16) ---------
__global__ __launch_bounds__(64) void k_pack(
    const float* __restrict__ W_hh_f, const float* __restrict__ wW_hh_f, const float* __restrict__ aW_hh_f,
    const float* __restrict__ W_hh_b, const float* __restrict__ wW_hh_b, const float* __restrict__ aW_hh_b,
    unsigned short* __restrict__ Wpk)
{
  const int T = blockIdx.x, dir = blockIdx.y;
  const int lane = threadIdx.x;
  const float* Wg = dir ? W_hh_b  : W_hh_f;
  const float* Ww = dir ? wW_hh_b : wW_hh_f;
  const float* Wa = dir ? aW_hh_b : aW_hh_f;
  for (int ks = 0; ks < 8; ++ks) {
    bf16x8 sv;
#pragma unroll
    for (int e = 0; e < 8; ++e) {
      const int k = ks * 32 + (lane >> 4) * 8 + e;
      float f;
      if (T < 96) {
        const int c = T * 16 + (lane & 15);
        f = (c < H3) ? Wg[(size_t)k * H3 + c] : Ww[(size_t)k * H3 + (c - H3)];
      } else {
        const int c = (T - 96) * 16 + (lane & 15);
        f = Wa[(size_t)k * H + c];
      }
      sv[e] = (short)f2bf(f);
    }
    *(bf16x8*)(Wpk + (((size_t)dir * 112 + T) * 8 + ks) * 512 + lane * 8) = sv;
  }
}

// ---------------- K1: char embedding -> gate / alpha input preacts ----------
__global__ __launch_bounds__(256) void k_embed(
    const int* __restrict__ inputs, const float* __restrict__ E,
    const float* __restrict__ W_ih_f, const float* __restrict__ b_f,
    const float* __restrict__ aW_ih_f, const float* __restrict__ ab_f,
    const float* __restrict__ W_ih_b, const float* __restrict__ b_b,
    const float* __restrict__ aW_ih_b, const float* __restrict__ ab_b,
    __hip_bfloat16* __restrict__ xg, float* __restrict__ xa)
{
  const int t = blockIdx.x, dir = blockIdx.y;
  const int tid = threadIdx.x;
  const float* W_ih = dir ? W_ih_b : W_ih_f;
  const float* bb   = dir ? b_b    : b_f;
  const float* aW   = dir ? aW_ih_b : aW_ih_f;
  const float* ab   = dir ? ab_b   : ab_f;
  const int src = dir ? (TSEQ - 1 - t) : t;

  __shared__ float xr[DEMB];
  if (tid < DEMB) xr[tid] = E[(size_t)inputs[src] * DEMB + tid];
  __syncthreads();

  float a0 = bb[tid], a1 = bb[H + tid], a2 = bb[2 * H + tid], a3 = ab[tid];
  for (int r = 0; r < DEMB; r += 4) {
    const float4 e4 = *reinterpret_cast<const float4*>(&xr[r]);
    const float ev[4] = {e4.x, e4.y, e4.z, e4.w};
#pragma unroll
    for (int kk = 0; kk < 4; ++kk) {
      const float* wp = W_ih + (size_t)(r + kk) * H3 + tid;
      a0 += ev[kk] * wp[0];
      a1 += ev[kk] * wp[H];
      a2 += ev[kk] * wp[2 * H];
      a3 += ev[kk] * aW[(size_t)(r + kk) * H + tid];
    }
  }
  __hip_bfloat16* xgrow = xg + ((size_t)dir * TSEQ + t) * H3;
  xgrow[tid]         = __float2bfloat16(a0);
  xgrow[H + tid]     = __float2bfloat16(a1);
  xgrow[2 * H + tid] = __float2bfloat16(a2);
  xa[((size_t)dir * TSEQ + t) * H + tid] = a3;
}

// ---------------- K2: word-gate preacts (valid slots only), bf16 out --------
__global__ __launch_bounds__(256) void k_wordgates(
    const int* __restrict__ fw_ids, const int* __restrict__ fw_mask,
    const int* __restrict__ bw_ids, const int* __restrict__ bw_mask,
    const float* __restrict__ word_table,
    const float* __restrict__ wW_ih_f, const float* __restrict__ wb_f,
    const float* __restrict__ wW_ih_b, const float* __restrict__ wb_b,
    __hip_bfloat16* __restrict__ wg)
{
  const int t = blockIdx.x, dir = blockIdx.y;
  const int tid = threadIdx.x;
  const int* ids = (dir ? bw_ids : fw_ids) + t * KEND;
  const int* msk = (dir ? bw_mask : fw_mask) + t * KEND;
  const float* wW = dir ? wW_ih_b : wW_ih_f;
  const float* wb = dir ? wb_b    : wb_f;

  __shared__ float we[KEND][WD];
  for (int w = 0; w < KEND; ++w) {
    if (msk[w]) {
      const float* src = word_table + (size_t)ids[w] * WD;
      for (int i = tid; i < WD; i += 256) we[w][i] = src[i];
    }
  }
  __syncthreads();

  __hip_bfloat16* out = wg + ((size_t)dir * TSEQ + t) * KEND * H3;
  for (int w = 0; w < KEND; ++w) {
    if (!msk[w]) continue;
    float a0 = wb[tid], a1 = wb[H + tid], a2 = wb[2 * H + tid];
    for (int r = 0; r < WD; r += 4) {
      const float4 e4 = *reinterpret_cast<const float4*>(&we[w][r]);
      const float ev[4] = {e4.x, e4.y, e4.z, e4.w};
#pragma unroll
      for (int kk = 0; kk < 4; ++kk) {
        const float* wp = wW + (size_t)(r + kk) * H3 + tid;
        a0 += ev[kk] * wp[0];
        a1 += ev[kk] * wp[H];
        a2 += ev[kk] * wp[2 * H];
      }
    }
    out[w * H3 + tid]         = __float2bfloat16(a0);
    out[w * H3 + H + tid]     = __float2bfloat16(a1);
    out[w * H3 + 2 * H + tid] = __float2bfloat16(a2);
  }
}

// ---------------- K3: scan; active blocks {0,8}=dir0, {1,9}=dir1 ------------
__global__ __launch_bounds__(NTH, 1) void k_scan(
    const __hip_bfloat16* __restrict__ xg, const float* __restrict__ xa,
    const __hip_bfloat16* __restrict__ wgG, float* __restrict__ hseq,
    const int* __restrict__ fw_start, const int* __restrict__ fw_mask,
    const int* __restrict__ bw_start, const int* __restrict__ bw_mask,
    const unsigned short* __restrict__ Wpk,
    unsigned long long* __restrict__ xb, unsigned* __restrict__ xf)
{
  const int gid = blockIdx.x;
  if (gid != 0 && gid != 1 && gid != 8 && gid != 9) return;  // same-XCD pairs
  const int dir  = gid & 1;
  const int side = gid >> 3;

  extern __shared__ char smem[];
  unsigned short* A1_16 = (unsigned short*)(smem + LO_A1);
  unsigned short* vS16  = (unsigned short*)(smem + LO_VS);
  unsigned short* ur16  = (unsigned short*)(smem + LO_UR);
  float* ringC = (float*)(smem + LO_RC);
  unsigned short* awS16 = (unsigned short*)(smem + LO_AWS);
  int* metaI = (int*)(smem + LO_MT);

  const int tid  = threadIdx.x;
  const int lane = tid & 63;
  const int wv   = tid >> 6;          // wave 0..3
  const int lmod = lane & 15;
  const int lgrp = lane >> 4;

  const int* startA = dir ? bw_start : fw_start;
  const int* maskA  = dir ? bw_mask  : fw_mask;
  const char* WpkD = (const char*)(Wpk + (size_t)dir * 112 * 8 * 512);

  unsigned long long* myPay = xb + (size_t)((dir * 2 + side) * 2) * 192;
  const unsigned long long* peerPay = xb + (size_t)((dir * 2 + (side ^ 1)) * 2) * 192;
  unsigned* myFlag   = xf + (dir * 2 + side) * 32;
  unsigned* peerFlag = xf + (dir * 2 + (side ^ 1)) * 32;

  // ---- one-time: 12 gate tiles/wave -> registers (builtin MFMA path) -------
  bf16x8 rW[12][8];
  {
    const char* rp = WpkD + (size_t)(side * 48 + wv * 12) * 8192 + lane * 16;
#pragma unroll
    for (int n = 0; n < 12; ++n)
#pragma unroll
      for (int ks = 0; ks < 8; ++ks)
        rW[n][ks] = *(const bf16x8*)(rp + (n * 8 + ks) * 1024);
  }
  // ---- one-time: 16 alpha tiles -> LDS -------------------------------------
  for (int o = tid * 16; o < 131072; o += NTH * 16)
    *(uint4*)(smem + LO_AT + o) = *(const uint4*)(WpkD + (size_t)96 * 8192 + o);
  // zero A1 / A2 / ringC
  if (tid < 32) *(uint4*)(smem + LO_A1 + tid * 16) = uint4{0, 0, 0, 0};
  for (int o = tid * 16; o < 4224; o += NTH * 16)
    *(uint4*)(smem + LO_A2 + o) = uint4{0, 0, 0, 0};
  for (int o = tid * 16; o < 8192; o += NTH * 16)
    *(uint4*)(smem + LO_RC + o) = uint4{0, 0, 0, 0};

  // ---- prologue: prefetch t=0, compact meta[0] -----------------------------
  unsigned nxI = 0, nxO = 0, nxG = 0; float nxA = 0.f;
  unsigned cxI = 0, cxO = 0, cxG = 0; float cxA = 0.f;
  int nmt = 0;
  {
    const unsigned short* xr = (const unsigned short*)(xg + (size_t)dir * TSEQ * H3);
    nxI = xr[tid]; nxO = xr[H + tid]; nxG = xr[2 * H + tid];
    nxA = xa[(size_t)dir * TSEQ * H + tid];
    if (wv == 3) {
      if (lane < 8) nmt = maskA[lane];
      else if (lane < 16) nmt = startA[lane - 8];
    }
  }
  __syncthreads();
  if (wv == 3) {
    int mAll[8], sAll[8];
#pragma unroll
    for (int s = 0; s < 8; ++s) { mAll[s] = __shfl(nmt, s); sAll[s] = __shfl(nmt, 8 + s); }
    if (lane == 0) {
      int n = 0;
      for (int s = 0; s < 8; ++s)
        if (mAll[s]) { metaI[1 + n] = s; metaI[9 + n] = sAll[s]; ++n; }
      metaI[0] = n;
    }
  }
  cxI = nxI; cxO = nxO; cxG = nxG; cxA = nxA;
  __syncthreads();

  // ---- main loop -----------------------------------------------------------
  for (int t = 0; t < TSEQ; ++t) {
    const int par = t & 1;
    const int* mp = metaI + par * 32;
    const int nw = mp[0];
    const int us7 = (t + 6) % 7;                    // slot for s = t-1
    unsigned short* stage16 = side ? (ur16 + us7 * 768) : vS16;
    unsigned short* rcv16   = side ? vS16 : (ur16 + us7 * 768);
    int hasL2w = 0;                                 // any len-2 word (uniform)
    for (int w = 0; w < nw; ++w) hasL2w |= (mp[9 + w] == t - 1);

    // -- issue wg(t) loads for this step's word cells (registers) ------------
    unsigned short wgv[24];
#pragma unroll
    for (int it = 0; it < 8; ++it) {
      const int u0 = tid + it * NTH;
      if (u0 < nw * 256) {
        const int w = u0 >> 8, j = u0 & 255;
        const int slot = mp[1 + w];
        const unsigned short* wgp =
            (const unsigned short*)wgG + ((size_t)(dir * TSEQ + t) * KEND + slot) * H3 + j;
        wgv[it * 3 + 0] = wgp[0];
        wgv[it * 3 + 1] = wgp[256];
        wgv[it * 3 + 2] = wgp[512];
      }
    }

    // ======== S1: own half of [v|u] = h(t-1) @ W  (2 groups of 6 tiles) =====
#pragma unroll
    for (int g = 0; g < 2; ++g) {
      f32x4 acc[6];
#pragma unroll
      for (int n = 0; n < 6; ++n) acc[n] = f32x4{0.f, 0.f, 0.f, 0.f};
#pragma unroll
      for (int ks = 0; ks < 8; ++ks) {
        const bf16x8 av = *(const bf16x8*)(smem + LO_A1 + ks * 64 + lgrp * 16);
#pragma unroll
        for (int n = 0; n < 6; ++n)
          acc[n] = __builtin_amdgcn_mfma_f32_16x16x32_bf16(av, rW[g * 6 + n][ks], acc[n], 0, 0, 0);
      }
      if (lane < 16) {
#pragma unroll
        for (int n = 0; n < 6; ++n)
          stage16[(wv * 12 + g * 6 + n) * 16 + lane] = (unsigned short)f2bf(acc[n][0]);
      }
    }
    __syncthreads();   // bar1: stage complete

    // -- publish (192x8B agent atomics) --------------------------------------
    if (tid < 192) {
      const unsigned long long q = *(const unsigned long long*)((const char*)stage16 + tid * 8);
      __hip_atomic_store(myPay + par * 192 + tid, q, __ATOMIC_RELAXED, __HIP_MEMORY_SCOPE_AGENT);
    }
    __syncthreads();   // bar2: payload stores drained (per-wave vmcnt 0)

    // -- FLAG EARLY (the single schedule delta vs round 7) -------------------
    if (tid == 0)
      __hip_atomic_store(myFlag, (unsigned)(t + 1), __ATOMIC_RELAXED, __HIP_MEMORY_SCOPE_AGENT);

    // -- prefetch t+1 inputs + S2a (side1: all; side0: s<=t-2) ---------------
    {
      const int tn = (t + 1 < TSEQ) ? t + 1 : TSEQ - 1;
      const unsigned short* xr = (const unsigned short*)(xg + ((size_t)dir * TSEQ + tn) * H3);
      nxI = xr[tid]; nxO = xr[H + tid]; nxG = xr[2 * H + tid];
      nxA = xa[((size_t)dir * TSEQ + tn) * H + tid];
      if (wv == 3) {
        if (lane < 8) nmt = maskA[tn * KEND + lane];
        else if (lane < 16) nmt = startA[tn * KEND + (lane - 8)];
      }
    }
#pragma unroll
    for (int it = 0; it < 8; ++it) {
      const int u0 = tid + it * NTH;
      if (u0 < nw * 256) {
        const int w = u0 >> 8, j = u0 & 255;
        const int s = mp[9 + w];
        if (side == 1 || s != t - 1) {
          const unsigned short* ur = ur16 + (s % 7) * 768;
          const float wi  = bf2f(wgv[it * 3 + 0]) + bf2f(ur[j]);
          const float wf  = bf2f(wgv[it * 3 + 1]) + bf2f(ur[256 + j]);
          const float wgg = bf2f(wgv[it * 3 + 2]) + bf2f(ur[512 + j]);
          const float cs  = ringC[(s & 7) * 256 + j];
          const float cv  = sigf(wf) * cs + sigf(wi) * tanhf(wgg);
          *(unsigned short*)(smem + LO_A2 + w * 528 + j * 2) = (unsigned short)f2bf(cv);
        }
      }
    }

    // -- poll (peer's early flag should already be visible) ------------------
    if (tid == 0) {
      while (__hip_atomic_load(peerFlag, __ATOMIC_RELAXED, __HIP_MEMORY_SCOPE_AGENT) < (unsigned)(t + 1))
        __builtin_amdgcn_s_sleep(1);
    }
    __syncthreads();   // bar3: peer payload published, S2a done

    if (tid < 192) {
      const unsigned long long q =
          __hip_atomic_load(peerPay + par * 192 + tid, __ATOMIC_RELAXED, __HIP_MEMORY_SCOPE_AGENT);
      *(unsigned long long*)((char*)rcv16 + tid * 8) = q;
    }
    __syncthreads();   // bar4: vS + u(t-1) complete on both sides

    // ======== S2b: side0, len-2 words (need received u(t-1)) ================
    if (hasL2w) {
      if (side == 0) {
#pragma unroll
        for (int it = 0; it < 8; ++it) {
          const int u0 = tid + it * NTH;
          if (u0 < nw * 256) {
            const int w = u0 >> 8, j = u0 & 255;
            const int s = mp[9 + w];
            if (s == t - 1) {
              const unsigned short* ur = ur16 + (s % 7) * 768;
              const float wi  = bf2f(wgv[it * 3 + 0]) + bf2f(ur[j]);
              const float wf  = bf2f(wgv[it * 3 + 1]) + bf2f(ur[256 + j]);
              const float wgg = bf2f(wgv[it * 3 + 2]) + bf2f(ur[512 + j]);
              const float cs  = ringC[(s & 7) * 256 + j];
              const float cv  = sigf(wf) * cs + sigf(wi) * tanhf(wgg);
              *(unsigned short*)(smem + LO_A2 + w * 528 + j * 2) = (unsigned short)f2bf(cv);
            }
          }
        }
      }
      __syncthreads();   // bar5 (only when a len-2 word exists): A2 complete
    }

    // ======== S3: alpha matvec aw = cw @ aW_hh (4 LDS tiles/wave) ===========
    if (nw > 0) {
      const int r2 = (lmod > 7) ? 7 : lmod;
      f32x4 ac[4];
#pragma unroll
      for (int m = 0; m < 4; ++m) ac[m] = f32x4{0.f, 0.f, 0.f, 0.f};
#pragma unroll
      for (int ks = 0; ks < 8; ++ks) {
        const bf16x8 a2v = *(const bf16x8*)(smem + LO_A2 + r2 * 528 + ks * 64 + lgrp * 16);
#pragma unroll
        for (int m = 0; m < 4; ++m) {
          const bf16x8 b = *(const bf16x8*)(smem + LO_AT + (size_t)(wv * 4 + m) * 8192 + ks * 1024 + lane * 16);
          ac[m] = __builtin_amdgcn_mfma_f32_16x16x32_bf16(a2v, b, ac[m], 0, 0, 0);
        }
      }
#pragma unroll
      for (int m = 0; m < 4; ++m) {
#pragma unroll
        for (int r = 0; r < 4; ++r) {
          const int row = lgrp * 4 + r;
          if (row < nw) awS16[row * 256 + (wv * 4 + m) * 16 + lmod] = (unsigned short)f2bf(ac[m][r]);
        }
      }
    }
    __syncthreads();   // bar6: awS ready

    // ======== S4: merge + state update (redundant, bit-identical) ===========
    {
      const int j = tid;
      const float i_s = sigf(bf2f(cxI) + bf2f(vS16[j]));
      const float o_s = sigf(bf2f(cxO) + bf2f(vS16[256 + j]));
      const float g_t = tanhf(bf2f(cxG) + bf2f(vS16[512 + j]));
      float cnew;
      if (nw > 0) {
        const float e_i = expf(i_s);
        float num = e_i * g_t, den = e_i;
        for (int w = 0; w < nw; ++w) {
          const float a  = sigf(cxA + bf2f(awS16[w * 256 + j]));
          const float ea = expf(a);
          num += ea * bf2f(*(const unsigned short*)(smem + LO_A2 + w * 528 + j * 2));
          den += ea;
        }
        cnew = num / den;
      } else {
        cnew = (1.f - i_s) * ringC[((t - 1) & 7) * 256 + j] + i_s * g_t;
      }
      const float hnew = o_s * tanhf(cnew);
      ringC[(t & 7) * 256 + j] = cnew;
      A1_16[j] = (unsigned short)f2bf(hnew);
      if ((side == 0) == (j < 128))                       // balanced skew
        hseq[((size_t)dir * TSEQ + t) * H + j] = hnew;
    }
    if (wv == 3) {
      int mAll[8], sAll[8];
#pragma unroll
      for (int s = 0; s < 8; ++s) { mAll[s] = __shfl(nmt, s); sAll[s] = __shfl(nmt, 8 + s); }
      if (lane == 0) {
        int* mq = metaI + ((t + 1) & 1) * 32;
        int n = 0;
        for (int s = 0; s < 8; ++s)
          if (mAll[s]) { mq[1 + n] = s; mq[9 + n] = sAll[s]; ++n; }
        mq[0] = n;
      }
    }
    cxI = nxI; cxO = nxO; cxG = nxG; cxA = nxA;
    __syncthreads();   // bar7: A1/ringC/meta ready for t+1
  }
}

// ---------------- K4: output projection -------------------------------------
__global__ __launch_bounds__(64) void k_proj(
    const float* __restrict__ hseq, const float* __restrict__ W_lin,
    const float* __restrict__ b_lin, float* __restrict__ out)
{
  const int t = blockIdx.x;
  const int tid = threadIdx.x;
  __shared__ float hrow[2 * H];
  for (int i = tid; i < H; i += 64) {
    hrow[i]     = hseq[(size_t)t * H + i];
    hrow[H + i] = hseq[((size_t)TSEQ + (TSEQ - 1 - t)) * H + i];
  }
  __syncthreads();
  if (tid < CCLS) {
    float acc = b_lin[tid];
    for (int j = 0; j < 2 * H; ++j) acc += hrow[j] * W_lin[(size_t)j * CCLS + tid];
    out[(size_t)t * CCLS + tid] = acc;
  }
}

// ---------------------------------------------------------------------------
extern "C" void kernel_launch(void* const* d_in, const int* in_sizes, int n_in,
                              void* d_out, int out_size, void* d_ws, size_t ws_size,
                              hipStream_t stream)
{
  const int* inputs   = (const int*)d_in[0];
  const int* fw_ids   = (const int*)d_in[1];
  const int* fw_start = (const int*)d_in[2];
  const int* fw_mask  = (const int*)d_in[3];
  const int* bw_ids   = (const int*)d_in[4];
  const int* bw_start = (const int*)d_in[5];
  const int* bw_mask  = (const int*)d_in[6];
  const float* E          = (const float*)d_in[8];
  const float* word_table = (const float*)d_in[9];
  const float* W_lin      = (const float*)d_in[10];
  const float* b_lin      = (const float*)d_in[11];
  const float* fw_W_ih  = (const float*)d_in[12];
  const float* fw_W_hh  = (const float*)d_in[13];
  const float* fw_b     = (const float*)d_in[14];
  const float* fw_aW_ih = (const float*)d_in[15];
  const float* fw_aW_hh = (const float*)d_in[16];
  const float* fw_ab    = (const float*)d_in[17];
  const float* fw_wW_ih = (const float*)d_in[18];
  const float* fw_wW_hh = (const float*)d_in[19];
  const float* fw_wb    = (const float*)d_in[20];
  const float* bw_W_ih  = (const float*)d_in[21];
  const float* bw_W_hh  = (const float*)d_in[22];
  const float* bw_b     = (const float*)d_in[23];
  const float* bw_aW_ih = (const float*)d_in[24];
  const float* bw_aW_hh = (const float*)d_in[25];
  const float* bw_ab    = (const float*)d_in[26];
  const float* bw_wW_ih = (const float*)d_in[27];
  const float* bw_wW_hh = (const float*)d_in[28];
  const float* bw_wb    = (const float*)d_in[29];

  char* p = (char*)d_ws;
  __hip_bfloat16* xg = (__hip_bfloat16*)p;  p += (size_t)2 * TSEQ * H3 * 2;        // 6.3 MB
  float* xa   = (float*)p;                  p += (size_t)2 * TSEQ * H * 4;         // 4.2 MB
  float* hseq = (float*)p;                  p += (size_t)2 * TSEQ * H * 4;         // 4.2 MB
  __hip_bfloat16* wg = (__hip_bfloat16*)p;  p += (size_t)2 * TSEQ * KEND * H3 * 2; // 50.3 MB
  unsigned short* Wpk = (unsigned short*)p; p += (size_t)2 * 112 * 8 * 512 * 2;    // 1.8 MB
  unsigned long long* xb = (unsigned long long*)p; p += (size_t)2 * 2 * 2 * 192 * 8; // 12 KB
  unsigned* xf = (unsigned*)p;              p += 512;

  hipFuncSetAttribute((const void*)k_scan,
                      hipFuncAttributeMaxDynamicSharedMemorySize, SMEM_SCAN);
  hipMemsetAsync(xf, 0, 512, stream);

  k_pack<<<dim3(112, 2), 64, 0, stream>>>(
      fw_W_hh, fw_wW_hh, fw_aW_hh, bw_W_hh, bw_wW_hh, bw_aW_hh, Wpk);
  k_embed<<<dim3(TSEQ, 2), 256, 0, stream>>>(
      inputs, E, fw_W_ih, fw_b, fw_aW_ih, fw_ab, bw_W_ih, bw_b, bw_aW_ih, bw_ab, xg, xa);
  k_wordgates<<<dim3(TSEQ, 2), 256, 0, stream>>>(
      fw_ids, fw_mask, bw_ids, bw_mask, word_table, fw_wW_ih, fw_wb, bw_wW_ih, bw_wb, wg);
  k_scan<<<16, NTH, SMEM_SCAN, stream>>>(
      xg, xa, wg, hseq, fw_start, fw_mask, bw_start, bw_mask, Wpk, xb, xf);
  k_proj<<<TSEQ, 64, 0, stream>>>(hseq, W_lin, b_lin, (float*)d_out);
}